// Round 6
// baseline (548.679 us; speedup 1.0000x reference)
//
#include <hip/hip_runtime.h>
#include <hip/hip_bf16.h>
#include <hip/hip_cooperative_groups.h>

namespace cg = cooperative_groups;

#define NN 12288
#define ED 256
#define ES 32
#define NE (2*NN - 1)     // N self-loops + N-1 parent->child edges
#define NBLK 512          // 2 blocks/CU -> coop co-residency guaranteed
#define NTHR 256
#define NT (NBLK * NTHR)  // 131072 grid threads

typedef __hip_bfloat16 bf16;

__device__ __forceinline__ float ldf(const void* p, int i, int f32) {
    return f32 ? ((const float*)p)[i]
               : __bfloat162float(((const bf16*)p)[i]);
}

// ============================ cooperative path ============================
// Whole 2-layer GCN in one dispatch. Phases separated by fence + grid.sync.
__global__ __launch_bounds__(NTHR, 4)
void k_gcn(const int* __restrict__ node_ids,
           const int* __restrict__ edges,
           const void* __restrict__ table,
           const void* __restrict__ W1,
           const void* __restrict__ b1,
           const void* __restrict__ W2,
           const void* __restrict__ b2,
           unsigned int* __restrict__ deg,
           float* __restrict__ acc1,
           float* __restrict__ acc2,
           float* __restrict__ xbuf,
           void* __restrict__ out) {
    cg::grid_group grid = cg::this_grid();
    const int tid0 = blockIdx.x * NTHR + threadIdx.x;

    // Per-block dtype detect: fp32 storage read as bf16 -> random-exponent
    // halfwords -> huge values; genuine bf16 -> |v| <~ 1.5. Deterministic.
    __shared__ int s_flag;
    if (threadIdx.x == 0) s_flag = 0;
    __syncthreads();
    {
        const bf16* p = (const bf16*)W1;
        bool huge = false;
        for (int k = threadIdx.x; k < 512; k += NTHR) {
            float v = __bfloat162float(p[k]);
            if (v > 1e4f || v < -1e4f) huge = true;
        }
        if (huge) atomicOr(&s_flag, 1);
    }
    __syncthreads();
    const int f32 = s_flag;

    // P0: zero deg/acc1/acc2 (ws is poisoned each launch)
    for (int i = tid0; i < NN * ES; i += NT) { acc1[i] = 0.f; acc2[i] = 0.f; }
    for (int i = tid0; i < NN; i += NT) deg[i] = 0u;
    __threadfence();
    grid.sync();

    // P1: degree histogram + X1 = emb@W1 + b1
    for (int i = tid0; i < NE; i += NT) atomicAdd(&deg[edges[2 * i]], 1u);
    for (int i = tid0; i < NN * ES; i += NT) {
        int n = i >> 5, j = i & 31;
        float acc;
        if (f32) {
            acc = ((const float*)b1)[j];
            const float4* e4 = (const float4*)((const float*)table + (size_t)node_ids[n] * ED);
            const float* w = (const float*)W1;
            #pragma unroll 4
            for (int k4 = 0; k4 < ED / 4; ++k4) {
                float4 e = e4[k4];
                int k = k4 * 4;
                acc += e.x * w[(k + 0) * ES + j];
                acc += e.y * w[(k + 1) * ES + j];
                acc += e.z * w[(k + 2) * ES + j];
                acc += e.w * w[(k + 3) * ES + j];
            }
        } else {
            acc = __bfloat162float(((const bf16*)b1)[j]);
            const bf16* e = (const bf16*)table + (size_t)node_ids[n] * ED;
            const bf16* w = (const bf16*)W1;
            #pragma unroll 8
            for (int k = 0; k < ED; ++k)
                acc += __bfloat162float(e[k]) * __bfloat162float(w[k * ES + j]);
        }
        xbuf[i] = acc;
    }
    __threadfence();
    grid.sync();

    // P2: acc1[r,:] += d[r]*d[c]*X1[c,:] per edge
    for (int i = tid0; i < NE * ES; i += NT) {
        int e = i >> 5, k = i & 31;
        int r = edges[2 * e], c = edges[2 * e + 1];
        float w = rsqrtf((float)deg[r]) * rsqrtf((float)deg[c]);
        atomicAdd(&acc1[r * ES + k], w * xbuf[c * ES + k]);
    }
    __threadfence();
    grid.sync();

    // P3: X2 = relu(acc1)@W2 + b2 (overwrites xbuf)
    for (int i = tid0; i < NN * ES; i += NT) {
        int n = i >> 5, j = i & 31;
        float acc;
        const float* h = acc1 + (size_t)n * ES;
        if (f32) {
            acc = ((const float*)b2)[j];
            const float* w2 = (const float*)W2;
            #pragma unroll
            for (int k = 0; k < ES; ++k) acc += fmaxf(h[k], 0.f) * w2[k * ES + j];
        } else {
            acc = __bfloat162float(((const bf16*)b2)[j]);
            const bf16* w2 = (const bf16*)W2;
            #pragma unroll
            for (int k = 0; k < ES; ++k)
                acc += fmaxf(h[k], 0.f) * __bfloat162float(w2[k * ES + j]);
        }
        xbuf[i] = acc;
    }
    __threadfence();
    grid.sync();

    // P4: acc2[r,:] += d[r]*d[c]*X2[c,:] per edge
    for (int i = tid0; i < NE * ES; i += NT) {
        int e = i >> 5, k = i & 31;
        int r = edges[2 * e], c = edges[2 * e + 1];
        float w = rsqrtf((float)deg[r]) * rsqrtf((float)deg[c]);
        atomicAdd(&acc2[r * ES + k], w * xbuf[c * ES + k]);
    }
    __threadfence();
    grid.sync();

    // P5: out = relu(acc2)
    for (int i = tid0; i < NN * ES; i += NT) {
        float v = fmaxf(acc2[i], 0.f);
        if (f32) ((float*)out)[i] = v;
        else     ((bf16*)out)[i] = __float2bfloat16(v);
    }
}

// ====================== fallback path (R5, known-good) ======================
__global__ void k_detect(const void* __restrict__ W1, int* __restrict__ flag) {
    const bf16* p = (const bf16*)W1;
    bool huge = false;
    for (int k = threadIdx.x; k < 512; k += 256) {
        float v = __bfloat162float(p[k]);
        if (v > 1e4f || v < -1e4f) huge = true;
    }
    if (huge) atomicOr(flag, 1);
}

__global__ void k_deg_x1(const int* __restrict__ node_ids,
                         const int* __restrict__ edges,
                         const void* __restrict__ table,
                         const void* __restrict__ W1,
                         const void* __restrict__ b1,
                         const int* __restrict__ flag,
                         unsigned int* __restrict__ deg,
                         float* __restrict__ X1) {
    int tid = blockIdx.x * blockDim.x + threadIdx.x;
    if (tid < NE) atomicAdd(&deg[edges[2 * tid]], 1u);
    int f32 = *flag;
    int n = tid >> 5, j = tid & 31;
    float acc = ldf(b1, j, f32);
    if (f32) {
        const float4* e4 = (const float4*)((const float*)table + (size_t)node_ids[n] * ED);
        const float* w = (const float*)W1;
        #pragma unroll 4
        for (int k4 = 0; k4 < ED / 4; ++k4) {
            float4 e = e4[k4];
            int k = k4 * 4;
            acc += e.x * w[(k + 0) * ES + j];
            acc += e.y * w[(k + 1) * ES + j];
            acc += e.z * w[(k + 2) * ES + j];
            acc += e.w * w[(k + 3) * ES + j];
        }
    } else {
        const bf16* e = (const bf16*)table + (size_t)node_ids[n] * ED;
        const bf16* w = (const bf16*)W1;
        #pragma unroll 8
        for (int k = 0; k < ED; ++k)
            acc += __bfloat162float(e[k]) * __bfloat162float(w[k * ES + j]);
    }
    X1[tid] = acc;
}

__global__ void k_scatter(const int* __restrict__ edges,
                          const unsigned int* __restrict__ deg,
                          const float* __restrict__ X,
                          float* __restrict__ acc) {
    int tid = blockIdx.x * blockDim.x + threadIdx.x;
    if (tid >= NE * ES) return;
    int e = tid >> 5, k = tid & 31;
    int r = edges[2 * e], c = edges[2 * e + 1];
    float w = rsqrtf((float)deg[r]) * rsqrtf((float)deg[c]);
    atomicAdd(&acc[r * ES + k], w * X[c * ES + k]);
}

__global__ void k_x2(const float* __restrict__ acc1,
                     const void* __restrict__ W2,
                     const void* __restrict__ b2,
                     const int* __restrict__ flag,
                     float* __restrict__ X2) {
    int tid = blockIdx.x * blockDim.x + threadIdx.x;
    int f32 = *flag;
    int n = tid >> 5, j = tid & 31;
    float acc = ldf(b2, j, f32);
    if (f32) {
        const float* w = (const float*)W2;
        #pragma unroll
        for (int k = 0; k < ES; ++k)
            acc += fmaxf(acc1[n * ES + k], 0.f) * w[k * ES + j];
    } else {
        const bf16* w = (const bf16*)W2;
        #pragma unroll
        for (int k = 0; k < ES; ++k)
            acc += fmaxf(acc1[n * ES + k], 0.f) * __bfloat162float(w[k * ES + j]);
    }
    X2[tid] = acc;
}

__global__ void k_out(const float* __restrict__ acc2,
                      const int* __restrict__ flag,
                      void* __restrict__ out) {
    int tid = blockIdx.x * blockDim.x + threadIdx.x;
    float v = fmaxf(acc2[tid], 0.f);
    if (*flag) ((float*)out)[tid] = v;
    else       ((bf16*)out)[tid] = __float2bfloat16(v);
}

extern "C" void kernel_launch(void* const* d_in, const int* in_sizes, int n_in,
                              void* d_out, int out_size, void* d_ws, size_t ws_size,
                              hipStream_t stream) {
    const int* node_ids = (const int*)d_in[0];
    const int* edges    = (const int*)d_in[1];
    const void* table   = d_in[2];
    const void* W1      = d_in[3];
    const void* b1      = d_in[4];
    const void* W2      = d_in[5];
    const void* b2      = d_in[6];

    // shared ws layout: [flag 256B][deg u32 NN][acc1][acc2][xbuf] (~4.8 MB)
    char* ws = (char*)d_ws;
    int* flag           = (int*)ws;
    unsigned int* deg   = (unsigned int*)(ws + 256);
    float* acc1         = (float*)(ws + 256 + (size_t)NN * 4);
    float* acc2         = acc1 + (size_t)NN * ES;
    float* xbuf         = acc2 + (size_t)NN * ES;
    void* out = d_out;

    // ---- try single cooperative dispatch (512 blocks: always co-resident) ----
    void* args[] = {(void*)&node_ids, (void*)&edges, (void*)&table,
                    (void*)&W1, (void*)&b1, (void*)&W2, (void*)&b2,
                    (void*)&deg, (void*)&acc1, (void*)&acc2,
                    (void*)&xbuf, (void*)&out};
    hipError_t err = hipLaunchCooperativeKernel((const void*)k_gcn, dim3(NBLK),
                                                dim3(NTHR), args, 0, stream);
    if (err == hipSuccess) return;
    (void)hipGetLastError();   // clear sticky error, take known-good path

    // ---- fallback: R5 six-dispatch chain (verbatim known-good) ----
    size_t zbytes = 256 + (size_t)NN * 4 + 2ull * NN * ES * 4;
    hipMemsetAsync(d_ws, 0, zbytes, stream);

    const int B = 256;
    int g_node = (NN * ES) / B;
    int g_edge = (NE * ES + B - 1) / B;

    k_detect <<<1, B, 0, stream>>>(W1, flag);
    k_deg_x1 <<<g_node, B, 0, stream>>>(node_ids, edges, table, W1, b1, flag, deg, xbuf);
    k_scatter<<<g_edge, B, 0, stream>>>(edges, deg, xbuf, acc1);
    k_x2     <<<g_node, B, 0, stream>>>(acc1, W2, b2, flag, xbuf);
    k_scatter<<<g_edge, B, 0, stream>>>(edges, deg, xbuf, acc2);
    k_out    <<<g_node, B, 0, stream>>>(acc2, flag, d_out);
}

// Round 7
// 280.606 us; speedup vs baseline: 1.9553x; 1.9553x over previous
//
#include <hip/hip_runtime.h>
#include <hip/hip_bf16.h>

#define NN 12288
#define ED 256
#define ES 32
#define NE (2*NN - 1)     // N self-loops + N-1 parent->child edges
#define NBLK 512          // 2 blocks/CU: coop co-residency guaranteed (proven R6)
#define NTHR 256
#define NT (NBLK * NTHR)  // 131072 grid threads

typedef __hip_bfloat16 bf16;

__device__ __forceinline__ float ldf(const void* p, int i, int f32) {
    return f32 ? ((const float*)p)[i]
               : __bfloat162float(((const bf16*)p)[i]);
}

// Hand-rolled grid barrier (sense-reversing, device scope). cnt and gen live
// on separate 128B cachelines in ws, zeroed by the memset node each launch.
// Arrive: acq_rel fetch_add chains all blocks' prior writes; last block
// releases gen+1; spinners acquire it. ~1-2us vs cg::grid.sync's ~93us (R6).
__device__ __forceinline__ void gridbar(unsigned* cnt, unsigned* gen) {
    __syncthreads();
    if (threadIdx.x == 0) {
        __threadfence();   // belt-and-braces agent-scope release of data
        unsigned g = __hip_atomic_load(gen, __ATOMIC_RELAXED, __HIP_MEMORY_SCOPE_AGENT);
        unsigned a = __hip_atomic_fetch_add(cnt, 1u, __ATOMIC_ACQ_REL, __HIP_MEMORY_SCOPE_AGENT);
        if (a == NBLK - 1) {
            // reset cnt BEFORE releasing gen: no other block can re-arrive
            // until it observes the new generation.
            __hip_atomic_store(cnt, 0u, __ATOMIC_RELAXED, __HIP_MEMORY_SCOPE_AGENT);
            __hip_atomic_store(gen, g + 1u, __ATOMIC_RELEASE, __HIP_MEMORY_SCOPE_AGENT);
        } else {
            while (__hip_atomic_load(gen, __ATOMIC_ACQUIRE, __HIP_MEMORY_SCOPE_AGENT) == g)
                __builtin_amdgcn_s_sleep(1);
        }
    }
    __syncthreads();
}

// ====================== single-dispatch cooperative path ======================
// deg/acc1/acc2/cnt/gen pre-zeroed by memset node. 4 custom barriers.
__global__ __launch_bounds__(NTHR, 4)
void k_gcn(const int* __restrict__ node_ids,
           const int* __restrict__ edges,
           const void* __restrict__ table,
           const void* __restrict__ W1,
           const void* __restrict__ b1,
           const void* __restrict__ W2,
           const void* __restrict__ b2,
           unsigned int* __restrict__ bar,     // [cnt @0, gen @32 words]
           unsigned int* __restrict__ deg,
           float* __restrict__ acc1,
           float* __restrict__ acc2,
           float* __restrict__ xbuf,
           void* __restrict__ out) {
    unsigned* cnt = bar;
    unsigned* gen = bar + 32;    // separate 128B cacheline
    const int tid0 = blockIdx.x * NTHR + threadIdx.x;

    // Per-block dtype detect (validated R6): fp32 read as bf16 -> huge values.
    __shared__ int s_flag;
    if (threadIdx.x == 0) s_flag = 0;
    __syncthreads();
    {
        const bf16* p = (const bf16*)W1;
        bool huge = false;
        for (int k = threadIdx.x; k < 512; k += NTHR) {
            float v = __bfloat162float(p[k]);
            if (v > 1e4f || v < -1e4f) huge = true;
        }
        if (huge) atomicOr(&s_flag, 1);
    }
    __syncthreads();
    const int f32 = s_flag;

    // P1: degree histogram + X1 = emb@W1 + b1
    for (int i = tid0; i < NE; i += NT) atomicAdd(&deg[edges[2 * i]], 1u);
    for (int i = tid0; i < NN * ES; i += NT) {
        int n = i >> 5, j = i & 31;
        float acc;
        if (f32) {
            acc = ((const float*)b1)[j];
            const float4* e4 = (const float4*)((const float*)table + (size_t)node_ids[n] * ED);
            const float* w = (const float*)W1;
            #pragma unroll 4
            for (int k4 = 0; k4 < ED / 4; ++k4) {
                float4 e = e4[k4];
                int k = k4 * 4;
                acc += e.x * w[(k + 0) * ES + j];
                acc += e.y * w[(k + 1) * ES + j];
                acc += e.z * w[(k + 2) * ES + j];
                acc += e.w * w[(k + 3) * ES + j];
            }
        } else {
            acc = __bfloat162float(((const bf16*)b1)[j]);
            const bf16* e = (const bf16*)table + (size_t)node_ids[n] * ED;
            const bf16* w = (const bf16*)W1;
            #pragma unroll 8
            for (int k = 0; k < ED; ++k)
                acc += __bfloat162float(e[k]) * __bfloat162float(w[k * ES + j]);
        }
        xbuf[i] = acc;
    }
    gridbar(cnt, gen);

    // P2: acc1[r,:] += d[r]*d[c]*X1[c,:] per edge
    for (int i = tid0; i < NE * ES; i += NT) {
        int e = i >> 5, k = i & 31;
        int r = edges[2 * e], c = edges[2 * e + 1];
        float w = rsqrtf((float)deg[r]) * rsqrtf((float)deg[c]);
        atomicAdd(&acc1[r * ES + k], w * xbuf[c * ES + k]);
    }
    gridbar(cnt, gen);

    // P3: X2 = relu(acc1)@W2 + b2 (overwrites xbuf)
    for (int i = tid0; i < NN * ES; i += NT) {
        int n = i >> 5, j = i & 31;
        float acc;
        const float* h = acc1 + (size_t)n * ES;
        if (f32) {
            acc = ((const float*)b2)[j];
            const float* w2 = (const float*)W2;
            #pragma unroll
            for (int k = 0; k < ES; ++k) acc += fmaxf(h[k], 0.f) * w2[k * ES + j];
        } else {
            acc = __bfloat162float(((const bf16*)b2)[j]);
            const bf16* w2 = (const bf16*)W2;
            #pragma unroll
            for (int k = 0; k < ES; ++k)
                acc += fmaxf(h[k], 0.f) * __bfloat162float(w2[k * ES + j]);
        }
        xbuf[i] = acc;
    }
    gridbar(cnt, gen);

    // P4: acc2[r,:] += d[r]*d[c]*X2[c,:] per edge
    for (int i = tid0; i < NE * ES; i += NT) {
        int e = i >> 5, k = i & 31;
        int r = edges[2 * e], c = edges[2 * e + 1];
        float w = rsqrtf((float)deg[r]) * rsqrtf((float)deg[c]);
        atomicAdd(&acc2[r * ES + k], w * xbuf[c * ES + k]);
    }
    gridbar(cnt, gen);

    // P5: out = relu(acc2)
    for (int i = tid0; i < NN * ES; i += NT) {
        float v = fmaxf(acc2[i], 0.f);
        if (f32) ((float*)out)[i] = v;
        else     ((bf16*)out)[i] = __float2bfloat16(v);
    }
}

// ====================== fallback path (R5, known-good) ======================
__global__ void k_detect(const void* __restrict__ W1, int* __restrict__ flag) {
    const bf16* p = (const bf16*)W1;
    bool huge = false;
    for (int k = threadIdx.x; k < 512; k += 256) {
        float v = __bfloat162float(p[k]);
        if (v > 1e4f || v < -1e4f) huge = true;
    }
    if (huge) atomicOr(flag, 1);
}

__global__ void k_deg_x1(const int* __restrict__ node_ids,
                         const int* __restrict__ edges,
                         const void* __restrict__ table,
                         const void* __restrict__ W1,
                         const void* __restrict__ b1,
                         const int* __restrict__ flag,
                         unsigned int* __restrict__ deg,
                         float* __restrict__ X1) {
    int tid = blockIdx.x * blockDim.x + threadIdx.x;
    if (tid < NE) atomicAdd(&deg[edges[2 * tid]], 1u);
    int f32 = *flag;
    int n = tid >> 5, j = tid & 31;
    float acc = ldf(b1, j, f32);
    if (f32) {
        const float4* e4 = (const float4*)((const float*)table + (size_t)node_ids[n] * ED);
        const float* w = (const float*)W1;
        #pragma unroll 4
        for (int k4 = 0; k4 < ED / 4; ++k4) {
            float4 e = e4[k4];
            int k = k4 * 4;
            acc += e.x * w[(k + 0) * ES + j];
            acc += e.y * w[(k + 1) * ES + j];
            acc += e.z * w[(k + 2) * ES + j];
            acc += e.w * w[(k + 3) * ES + j];
        }
    } else {
        const bf16* e = (const bf16*)table + (size_t)node_ids[n] * ED;
        const bf16* w = (const bf16*)W1;
        #pragma unroll 8
        for (int k = 0; k < ED; ++k)
            acc += __bfloat162float(e[k]) * __bfloat162float(w[k * ES + j]);
    }
    X1[tid] = acc;
}

__global__ void k_scatter(const int* __restrict__ edges,
                          const unsigned int* __restrict__ deg,
                          const float* __restrict__ X,
                          float* __restrict__ acc) {
    int tid = blockIdx.x * blockDim.x + threadIdx.x;
    if (tid >= NE * ES) return;
    int e = tid >> 5, k = tid & 31;
    int r = edges[2 * e], c = edges[2 * e + 1];
    float w = rsqrtf((float)deg[r]) * rsqrtf((float)deg[c]);
    atomicAdd(&acc[r * ES + k], w * X[c * ES + k]);
}

__global__ void k_x2(const float* __restrict__ acc1,
                     const void* __restrict__ W2,
                     const void* __restrict__ b2,
                     const int* __restrict__ flag,
                     float* __restrict__ X2) {
    int tid = blockIdx.x * blockDim.x + threadIdx.x;
    int f32 = *flag;
    int n = tid >> 5, j = tid & 31;
    float acc = ldf(b2, j, f32);
    if (f32) {
        const float* w = (const float*)W2;
        #pragma unroll
        for (int k = 0; k < ES; ++k)
            acc += fmaxf(acc1[n * ES + k], 0.f) * w[k * ES + j];
    } else {
        const bf16* w = (const bf16*)W2;
        #pragma unroll
        for (int k = 0; k < ES; ++k)
            acc += fmaxf(acc1[n * ES + k], 0.f) * __bfloat162float(w[k * ES + j]);
    }
    X2[tid] = acc;
}

__global__ void k_out(const float* __restrict__ acc2,
                      const int* __restrict__ flag,
                      void* __restrict__ out) {
    int tid = blockIdx.x * blockDim.x + threadIdx.x;
    float v = fmaxf(acc2[tid], 0.f);
    if (*flag) ((float*)out)[tid] = v;
    else       ((bf16*)out)[tid] = __float2bfloat16(v);
}

extern "C" void kernel_launch(void* const* d_in, const int* in_sizes, int n_in,
                              void* d_out, int out_size, void* d_ws, size_t ws_size,
                              hipStream_t stream) {
    const int* node_ids = (const int*)d_in[0];
    const int* edges    = (const int*)d_in[1];
    const void* table   = d_in[2];
    const void* W1      = d_in[3];
    const void* b1      = d_in[4];
    const void* W2      = d_in[5];
    const void* b2      = d_in[6];

    // ws layout: [bar/flag 256B][deg u32 NN][acc1][acc2][xbuf] (~4.8 MB)
    char* ws = (char*)d_ws;
    unsigned int* bar   = (unsigned int*)ws;          // cnt@word0, gen@word32
    int* flag           = (int*)(ws + 192);           // fallback-path flag
    unsigned int* deg   = (unsigned int*)(ws + 256);
    float* acc1         = (float*)(ws + 256 + (size_t)NN * 4);
    float* acc2         = acc1 + (size_t)NN * ES;
    float* xbuf         = acc2 + (size_t)NN * ES;
    void* out = d_out;

    // zero bar+flag+deg+acc1+acc2 (contiguous prefix, ~3.2 MB, ~0.7us)
    size_t zbytes = 256 + (size_t)NN * 4 + 2ull * NN * ES * 4;
    hipMemsetAsync(d_ws, 0, zbytes, stream);

    // ---- single cooperative dispatch with custom fast barrier ----
    void* args[] = {(void*)&node_ids, (void*)&edges, (void*)&table,
                    (void*)&W1, (void*)&b1, (void*)&W2, (void*)&b2,
                    (void*)&bar, (void*)&deg, (void*)&acc1, (void*)&acc2,
                    (void*)&xbuf, (void*)&out};
    hipError_t err = hipLaunchCooperativeKernel((const void*)k_gcn, dim3(NBLK),
                                                dim3(NTHR), args, 0, stream);
    if (err == hipSuccess) return;
    (void)hipGetLastError();   // clear sticky error, take known-good path

    // ---- fallback: R5 six-dispatch chain (verbatim known-good) ----
    const int B = 256;
    int g_node = (NN * ES) / B;
    int g_edge = (NE * ES + B - 1) / B;

    k_detect <<<1, B, 0, stream>>>(W1, flag);
    k_deg_x1 <<<g_node, B, 0, stream>>>(node_ids, edges, table, W1, b1, flag, deg, xbuf);
    k_scatter<<<g_edge, B, 0, stream>>>(edges, deg, xbuf, acc1);
    k_x2     <<<g_node, B, 0, stream>>>(acc1, W2, b2, flag, xbuf);
    k_scatter<<<g_edge, B, 0, stream>>>(edges, deg, xbuf, acc2);
    k_out    <<<g_node, B, 0, stream>>>(acc2, flag, d_out);
}